// Round 4
// baseline (4228.610 us; speedup 1.0000x reference)
//
#include <hip/hip_runtime.h>
#include <math.h>

// Problem constants (E,B,M,C) = (64, 512, 128, 128), sigma=0.5, eps=1e-6
#define MM   128
#define CC   128
#define EE   64
#define BB   512
#define LDT  132          // padded row stride for At in LDS
#define SIG2 0.25f
#define EPSV 1e-6f

// LDS layout (floats). At[128][132] + 12 vectors of 128 + 24 scalar slots.
#define AT_OFF   0
#define VEC_BASE (128*LDT)
#define VEC(i)   (VEC_BASE + (i)*128)
// 0 vz, 1 vaz, 2 vw0, 3 vt0, 4 vu1, 5 vwc, 6 vt2, 7 vvv, 8 vuw, 9 vdl, 10 vg1, 11 vg2
#define SC_OFF   (VEC_BASE + 12*128)
// scal: [0]=sig [1]=d2 [2]=s_uwg2 [3]=s_vg1 [4]=s_uwg1 [5] spare
//       [6..21]=epilogue wave sums [22]=GJ pivot
#define SMEM_FLOATS (SC_OFF + 24)
#define SMEM_BYTES  (SMEM_FLOATS * 4)        // 73,824 B

// ---------------------------------------------------------------------------
// Thread mapping (1024 threads): w = t>>6, l = t&63
//   r  = 64*(w&1) + l      (row owned, 0..127)
//   q  = w>>1  (0..7), cb = 16*q  (column chunk)
// A, U, Ginv rows live in REGISTERS (16 floats each). LDS holds A^T only
// (for the two A^T-matvec phases) + the step vectors.
// Matvec partials combine via LDS atomicAdd (ds_add_f32): within a wave the
// 64 lanes add to consecutive addresses -> one conflict-free instruction.
// NO second __launch_bounds__ arg (waves-per-eu minimum forces spill).
// ---------------------------------------------------------------------------

// In-place Gauss-Jordan inverse of (A A^T + SIG2*I), 1024 threads.
// Caller staged A row-major into T=[128][LDT] and synced. Destroys T;
// leaves Ginv in T (row-major). Mapping: rg = t>>3, cq = t&7, ccb = 16*cq.
__device__ __forceinline__ void ginv_inplace(float* sm, const int t) {
    float* T   = sm + AT_OFF;
    float* piv = sm + SC_OFF + 22;
    const int rg = t >> 3, cq = t & 7, ccb = cq << 4;
    float Gacc[16];
    #pragma unroll
    for (int j = 0; j < 16; ++j) Gacc[j] = 0.f;
    #pragma unroll 1
    for (int cc = 0; cc < 32; ++cc) {
        const float4 ar = *(const float4*)&T[rg*LDT + 4*cc];
        #pragma unroll
        for (int j = 0; j < 16; ++j) {
            const float4 br = *(const float4*)&T[(ccb + j)*LDT + 4*cc];
            Gacc[j] += ar.x*br.x + ar.y*br.y + ar.z*br.z + ar.w*br.w;
        }
    }
    #pragma unroll
    for (int j = 0; j < 16; ++j)
        if (ccb + j == rg) Gacc[j] += SIG2;
    __syncthreads();
    #pragma unroll
    for (int j4 = 0; j4 < 4; ++j4) {
        float4 v; v.x = Gacc[4*j4]; v.y = Gacc[4*j4+1]; v.z = Gacc[4*j4+2]; v.w = Gacc[4*j4+3];
        *(float4*)&T[rg*LDT + ccb + 4*j4] = v;
    }
    #pragma unroll 1
    for (int k = 0; k < 128; ++k) {
        const int kq = k >> 4;
        __syncthreads();
        if (rg == k && cq == kq) piv[0] = 1.0f / T[k*LDT + k];
        __syncthreads();
        if (rg == k) {
            const float pinv = piv[0];
            #pragma unroll
            for (int j4 = 0; j4 < 4; ++j4) {
                float4 g = *(float4*)&T[k*LDT + ccb + 4*j4];
                g.x *= pinv; g.y *= pinv; g.z *= pinv; g.w *= pinv;
                *(float4*)&T[k*LDT + ccb + 4*j4] = g;
            }
            if (cq == kq) T[k*LDT + k] = pinv;   // identity-column trick
        }
        __syncthreads();
        const float f = (rg == k) ? 0.f : T[rg*LDT + k];
        __syncthreads();
        if (rg != k) {
            #pragma unroll
            for (int j4 = 0; j4 < 4; ++j4) {
                float4 own = *(float4*)&T[rg*LDT + ccb + 4*j4];
                const float4 pv = *(const float4*)&T[k*LDT + ccb + 4*j4];
                own.x -= f*pv.x; own.y -= f*pv.y; own.z -= f*pv.z; own.w -= f*pv.w;
                *(float4*)&T[rg*LDT + ccb + 4*j4] = own;
            }
            if (cq == kq) T[rg*LDT + k] -= f;    // blind gave f - f*pinv; want -f*pinv
        }
    }
    __syncthreads();
}

__global__ __launch_bounds__(1024) void gpm_setup(const float* __restrict__ mean0,
                                                  float* __restrict__ ginv0) {
    extern __shared__ float sm[];
    float* T = sm + AT_OFF;
    const int t = threadIdx.x;
    const int rg = t >> 3, cq = t & 7, ccb = cq << 4;
    const float* src = mean0 + rg*CC + ccb;
    #pragma unroll
    for (int j4 = 0; j4 < 4; ++j4)
        *(float4*)&T[rg*LDT + ccb + 4*j4] = *(const float4*)&src[4*j4];
    __syncthreads();
    ginv_inplace(sm, t);
    #pragma unroll
    for (int j4 = 0; j4 < 4; ++j4)
        *(float4*)&ginv0[rg*CC + ccb + 4*j4] = *(const float4*)&T[rg*LDT + ccb + 4*j4];
}

// 3-level shuffle (8-lane groups) then 1-in-8 lanes atomic into a scalar slot
#define SC_ADD(slot, val) { float v_ = (val);                                 \
    v_ += __shfl_xor(v_, 1, 64); v_ += __shfl_xor(v_, 2, 64);                 \
    v_ += __shfl_xor(v_, 4, 64);                                              \
    if ((l & 7) == 0) atomicAdd(&scal[slot], v_); }

__global__ __launch_bounds__(1024) void gpm_main(
        const float* __restrict__ zin, const float* __restrict__ mean0,
        const float* __restrict__ lvar, float* __restrict__ out,
        const float* __restrict__ ginv0, const int use_ws) {
    extern __shared__ float sm[];
    float* At  = sm + AT_OFF;
    float* vz  = sm + VEC(0);
    float* vaz = sm + VEC(1);
    float* vw0 = sm + VEC(2);
    float* vt0 = sm + VEC(3);
    float* vu1 = sm + VEC(4);
    float* vwc = sm + VEC(5);
    float* vt2 = sm + VEC(6);
    float* vvv = sm + VEC(7);
    float* vuw = sm + VEC(8);
    float* vdl = sm + VEC(9);
    float* vg1 = sm + VEC(10);
    float* vg2 = sm + VEC(11);
    float* scal = sm + SC_OFF;

    const int t = threadIdx.x, b = blockIdx.x;
    const int w = t >> 6, l = t & 63;
    const int r  = ((w & 1) << 6) | l;
    const int q  = w >> 1;
    const int cb = q << 4;

    // zero all atomic-target vectors + scalar slots
    if (t < 1024)            sm[VEC_BASE + t] = 0.f;
    if (t < 12*128 - 1024)   sm[VEC_BASE + 1024 + t] = 0.f;
    if (t < 24)              scal[t] = 0.f;

    const float pvar = expf(lvar[0]) + EPSV;

    float Areg[16], Ureg[16], Greg[16];
    {
        const float* src = mean0 + r*CC + cb;
        #pragma unroll
        for (int j4 = 0; j4 < 4; ++j4) {
            const float4 v = *(const float4*)&src[4*j4];
            Areg[4*j4] = v.x; Areg[4*j4+1] = v.y; Areg[4*j4+2] = v.z; Areg[4*j4+3] = v.w;
        }
    }
    #pragma unroll
    for (int j = 0; j < 16; ++j) Ureg[j] = (cb + j == r) ? pvar : 0.f;

    if (use_ws) {
        const float* src = ginv0 + r*CC + cb;
        #pragma unroll
        for (int j4 = 0; j4 < 4; ++j4) {
            const float4 v = *(const float4*)&src[4*j4];
            Greg[4*j4] = v.x; Greg[4*j4+1] = v.y; Greg[4*j4+2] = v.z; Greg[4*j4+3] = v.w;
        }
    } else {
        // per-block fallback: stage A rows into At buffer, invert in place
        #pragma unroll
        for (int j4 = 0; j4 < 4; ++j4) {
            float4 v; v.x = Areg[4*j4]; v.y = Areg[4*j4+1]; v.z = Areg[4*j4+2]; v.w = Areg[4*j4+3];
            *(float4*)&At[r*LDT + cb + 4*j4] = v;
        }
        __syncthreads();
        ginv_inplace(sm, t);
        #pragma unroll
        for (int j4 = 0; j4 < 4; ++j4) {
            const float4 v = *(const float4*)&At[r*LDT + cb + 4*j4];
            Greg[4*j4] = v.x; Greg[4*j4+1] = v.y; Greg[4*j4+2] = v.z; Greg[4*j4+3] = v.w;
        }
        __syncthreads();       // done reading Ginv before At is overwritten
    }
    // At = A^T (column writes: consecutive lanes -> consecutive banks)
    #pragma unroll
    for (int j = 0; j < 16; ++j) At[(cb + j)*LDT + r] = Areg[j];
    if (t < 32)
        *(float4*)&vz[4*t] = *(const float4*)&zin[(size_t)b*CC + 4*t];
    __syncthreads();

    #pragma unroll 1
    for (int e = 0; e < EE; ++e) {
        // ---- L1: az = A z ; re-init this step's late accumulators ----
        {
            float s = 0.f;
            #pragma unroll
            for (int j4 = 0; j4 < 4; ++j4) {
                const float4 x = *(const float4*)&vz[cb + 4*j4];
                s += Areg[4*j4]*x.x + Areg[4*j4+1]*x.y + Areg[4*j4+2]*x.z + Areg[4*j4+3]*x.w;
            }
            atomicAdd(&vaz[r], s);
            if (t < 128) { vuw[t] = 0.f; vg1[t] = 0.f; vg2[t] = 0.f; }
            if (t == 512) { scal[0] = SIG2; scal[1] = 0.f; scal[2] = 0.f; scal[3] = 0.f; scal[4] = 0.f; }
        }
        __syncthreads();
        // ---- L2: w0 = Ginv az ----
        {
            float s = 0.f;
            #pragma unroll
            for (int j4 = 0; j4 < 4; ++j4) {
                const float4 x = *(const float4*)&vaz[cb + 4*j4];
                s += Greg[4*j4]*x.x + Greg[4*j4+1]*x.y + Greg[4*j4+2]*x.z + Greg[4*j4+3]*x.w;
            }
            atomicAdd(&vw0[r], s);
        }
        __syncthreads();
        // ---- L3: t0 = A^T w0 (rows of At) ----
        {
            float s = 0.f;
            #pragma unroll
            for (int j4 = 0; j4 < 4; ++j4) {
                const float4 a = *(const float4*)&At[r*LDT + cb + 4*j4];
                const float4 x = *(const float4*)&vw0[cb + 4*j4];
                s += a.x*x.x + a.y*x.y + a.z*x.z + a.w*x.w;
            }
            atomicAdd(&vt0[r], s);
        }
        __syncthreads();
        // ---- L4: u1 = A t0 ----
        {
            float s = 0.f;
            #pragma unroll
            for (int j4 = 0; j4 < 4; ++j4) {
                const float4 x = *(const float4*)&vt0[cb + 4*j4];
                s += Areg[4*j4]*x.x + Areg[4*j4+1]*x.y + Areg[4*j4+2]*x.z + Areg[4*j4+3]*x.w;
            }
            atomicAdd(&vu1[r], s);
        }
        __syncthreads();
        // ---- L5: wc = Ginv rr, rr = az - u1 - SIG2*w0 (fused reads) ----
        {
            float s = 0.f;
            #pragma unroll
            for (int j4 = 0; j4 < 4; ++j4) {
                const float4 az4 = *(const float4*)&vaz[cb + 4*j4];
                const float4 u14 = *(const float4*)&vu1[cb + 4*j4];
                const float4 w04 = *(const float4*)&vw0[cb + 4*j4];
                s += Greg[4*j4]  *(az4.x - u14.x - SIG2*w04.x)
                   + Greg[4*j4+1]*(az4.y - u14.y - SIG2*w04.y)
                   + Greg[4*j4+2]*(az4.z - u14.z - SIG2*w04.z)
                   + Greg[4*j4+3]*(az4.w - u14.w - SIG2*w04.w);
            }
            atomicAdd(&vwc[r], s);
        }
        __syncthreads();
        // ---- L6: t2 = A^T w ; uw = U w ; sig   (w = w0 + wc) ----
        {
            float s1 = 0.f, s2 = 0.f;
            #pragma unroll
            for (int j4 = 0; j4 < 4; ++j4) {
                const float4 a   = *(const float4*)&At[r*LDT + cb + 4*j4];
                const float4 w04 = *(const float4*)&vw0[cb + 4*j4];
                const float4 wc4 = *(const float4*)&vwc[cb + 4*j4];
                const float wx = w04.x + wc4.x, wy = w04.y + wc4.y;
                const float wz = w04.z + wc4.z, ww = w04.w + wc4.w;
                s1 += a.x*wx + a.y*wy + a.z*wz + a.w*ww;
                s2 += Ureg[4*j4]*wx + Ureg[4*j4+1]*wy + Ureg[4*j4+2]*wz + Ureg[4*j4+3]*ww;
            }
            atomicAdd(&vt2[r], s1);
            atomicAdd(&vuw[r], s2);
            const float w_r = vw0[r] + vwc[r];
            SC_ADD(0, s2 * w_r);                       // sig partial
        }
        __syncthreads();
        // ---- L7: vv = A dl (dl = z - t2) ; g2 = Ginv uw ; s_uwg2 ; d2 ; vdl ----
        {
            float s1 = 0.f, s2 = 0.f;
            #pragma unroll
            for (int j4 = 0; j4 < 4; ++j4) {
                const float4 z4  = *(const float4*)&vz[cb + 4*j4];
                const float4 t24 = *(const float4*)&vt2[cb + 4*j4];
                s1 += Areg[4*j4]  *(z4.x - t24.x) + Areg[4*j4+1]*(z4.y - t24.y)
                    + Areg[4*j4+2]*(z4.z - t24.z) + Areg[4*j4+3]*(z4.w - t24.w);
                const float4 u4  = *(const float4*)&vuw[cb + 4*j4];
                s2 += Greg[4*j4]*u4.x + Greg[4*j4+1]*u4.y + Greg[4*j4+2]*u4.z + Greg[4*j4+3]*u4.w;
            }
            atomicAdd(&vvv[r], s1);
            atomicAdd(&vg2[r], s2);
            SC_ADD(2, s2 * vuw[r]);                    // s_uwg2 partial
            if (t < 128) {
                const float dlv = vz[t] - vt2[t];
                vdl[t] = dlv;
                float d_ = dlv * dlv;
                d_ += __shfl_xor(d_, 1, 64); d_ += __shfl_xor(d_, 2, 64); d_ += __shfl_xor(d_, 4, 64);
                if ((l & 7) == 0) atomicAdd(&scal[1], d_);   // d2 partial
            }
        }
        __syncthreads();
        // ---- L8: g1 = Ginv vv ; s_vg1 ; s_uwg1 ----
        {
            float s = 0.f;
            #pragma unroll
            for (int j4 = 0; j4 < 4; ++j4) {
                const float4 x = *(const float4*)&vvv[cb + 4*j4];
                s += Greg[4*j4]*x.x + Greg[4*j4+1]*x.y + Greg[4*j4+2]*x.z + Greg[4*j4+3]*x.w;
            }
            atomicAdd(&vg1[r], s);
            SC_ADD(3, s * vvv[r]);                     // s_vg1 partial
            SC_ADD(4, s * vuw[r]);                     // s_uwg1 partial
        }
        __syncthreads();
        // ---- L9: rank updates of A,U,Ginv ; zero next accumulators ; next z ----
        {
            const float sig = scal[0];
            const float inv_sig = 1.0f / sig;
            const float d2v = scal[1];
            const float s_uwg2 = scal[2], s_vg1 = scal[3], s_uwg1 = scal[4];
            // 2x2 Woodbury capacitance: G_new = G + v c^T + c v^T + d2 c c^T
            const float b11 = s_vg1 - d2v;
            const float b12 = 1.0f + s_uwg1*inv_sig;
            const float b22 = s_uwg2*inv_sig*inv_sig;
            const float idet = 1.0f / (b11*b22 - b12*b12);
            const float K11 = b22*idet, K12v = -b12*idet, K22 = b11*idet;
            const float k12s = K12v*inv_sig, k22s = K22*inv_sig*inv_sig;
            const float cr  = vuw[r]*inv_sig;
            const float g1r = vg1[r], g2r = vg2[r];
            const float ar_ = K11*g1r + k12s*g2r;
            const float br_ = k12s*g1r + k22s*g2r;
            #pragma unroll
            for (int j4 = 0; j4 < 4; ++j4) {
                const float4 dd = *(const float4*)&vdl[cb + 4*j4];
                Areg[4*j4]   += cr*dd.x; Areg[4*j4+1] += cr*dd.y;
                Areg[4*j4+2] += cr*dd.z; Areg[4*j4+3] += cr*dd.w;
                const float4 uu = *(const float4*)&vuw[cb + 4*j4];
                Ureg[4*j4]   -= cr*uu.x; Ureg[4*j4+1] -= cr*uu.y;
                Ureg[4*j4+2] -= cr*uu.z; Ureg[4*j4+3] -= cr*uu.w;
                const float4 q1 = *(const float4*)&vg1[cb + 4*j4];
                const float4 q2 = *(const float4*)&vg2[cb + 4*j4];
                Greg[4*j4]   -= ar_*q1.x + br_*q2.x;
                Greg[4*j4+1] -= ar_*q1.y + br_*q2.y;
                Greg[4*j4+2] -= ar_*q1.z + br_*q2.z;
                Greg[4*j4+3] -= ar_*q1.w + br_*q2.w;
            }
            // write-through A^T
            #pragma unroll
            for (int j = 0; j < 16; ++j) At[(cb + j)*LDT + r] = Areg[j];
            // zero vaz,vw0,vt0,vu1,vwc,vt2,vvv (slots 1..7, contiguous)
            if (t < 896) (sm + VEC(1))[t] = 0.f;
            if (t < 32 && e + 1 < EE)
                *(float4*)&vz[4*t] = *(const float4*)&zin[((size_t)(e+1)*BB + b)*CC + 4*t];
        }
        __syncthreads();
    }

    // epilogue: post_mean from Areg
    {
        float* dst = out + (size_t)b*(MM*CC) + r*CC + cb;
        #pragma unroll
        for (int j4 = 0; j4 < 4; ++j4) {
            float4 v; v.x = Areg[4*j4]; v.y = Areg[4*j4+1]; v.z = Areg[4*j4+2]; v.w = Areg[4*j4+3];
            *(float4*)&dst[4*j4] = v;
        }
    }
    // post_cov from Ureg + diag extraction (static indexing)
    float qd = 1.f;
    {
        float* dst = out + (size_t)BB*(MM*CC) + (size_t)b*(MM*MM) + r*MM + cb;
        #pragma unroll
        for (int j4 = 0; j4 < 4; ++j4) {
            float4 v; v.x = Ureg[4*j4]; v.y = Ureg[4*j4+1]; v.z = Ureg[4*j4+2]; v.w = Ureg[4*j4+3];
            *(float4*)&dst[4*j4] = v;
            if (cb + 4*j4     == r) qd = v.x;
            if (cb + 4*j4 + 1 == r) qd = v.y;
            if (cb + 4*j4 + 2 == r) qd = v.z;
            if (cb + 4*j4 + 3 == r) qd = v.w;
        }
    }
    // dkl = mean_b[ C*sum(q/p) + sum((A-A0)^2)/p - C*M + C*sum(log p - log q) ]
    {
        const float inv_p = 1.0f / pvar;
        float acc = 0.f;
        const float* src = mean0 + r*CC + cb;
        #pragma unroll
        for (int j4 = 0; j4 < 4; ++j4) {
            const float4 a0 = *(const float4*)&src[4*j4];
            const float dx = Areg[4*j4]   - a0.x, dy = Areg[4*j4+1] - a0.y;
            const float dz = Areg[4*j4+2] - a0.z, dw = Areg[4*j4+3] - a0.w;
            acc += dx*dx + dy*dy + dz*dz + dw*dw;
        }
        float local = acc * inv_p;
        if (q == (r >> 4))   // owner of diagonal element of row r
            local += (float)CC * (qd*inv_p + logf(pvar) - logf(qd));
        #pragma unroll
        for (int m2 = 1; m2 < 64; m2 <<= 1) local += __shfl_xor(local, m2, 64);
        if (l == 0) scal[6 + w] = local;
        __syncthreads();
        if (t == 0) {
            float tot = 0.f;
            #pragma unroll
            for (int i = 0; i < 16; ++i) tot += scal[6 + i];
            tot -= (float)(CC*MM);
            atomicAdd(out + (size_t)2*BB*MM*CC, tot * (1.0f/(float)BB));
        }
    }
}

extern "C" void kernel_launch(void* const* d_in, const int* in_sizes, int n_in,
                              void* d_out, int out_size, void* d_ws, size_t ws_size,
                              hipStream_t stream) {
    (void)in_sizes; (void)n_in; (void)out_size;
    const float* zin   = (const float*)d_in[0];
    const float* mean0 = (const float*)d_in[1];
    const float* lvar  = (const float*)d_in[2];
    float* out = (float*)d_out;
    float* dkl = out + (size_t)2*BB*MM*CC;
    const int use_ws = (d_ws != nullptr && ws_size >= (size_t)MM*MM*4) ? 1 : 0;
    float* ginv0 = (float*)d_ws;

    hipFuncSetAttribute((const void*)gpm_setup, hipFuncAttributeMaxDynamicSharedMemorySize, SMEM_BYTES);
    hipFuncSetAttribute((const void*)gpm_main,  hipFuncAttributeMaxDynamicSharedMemorySize, SMEM_BYTES);

    hipMemsetAsync(dkl, 0, sizeof(float), stream);
    if (use_ws)
        gpm_setup<<<1, 1024, SMEM_BYTES, stream>>>(mean0, ginv0);
    gpm_main<<<BB, 1024, SMEM_BYTES, stream>>>(zin, mean0, lvar, out, ginv0, use_ws);
}

// Round 5
// 4133.064 us; speedup vs baseline: 1.0231x; 1.0231x over previous
//
#include <hip/hip_runtime.h>
#include <math.h>

// Problem constants (E,B,M,C) = (64, 512, 128, 128), sigma=0.5, eps=1e-6
#define MM   128
#define CC   128
#define EE   64
#define BB   512
#define LDT  132          // padded row stride for At in LDS
#define SIG2 0.25f
#define EPSV 1e-6f

// LDS layout (floats). At[128][132] + 12 vectors of 128 + 24 scalar slots.
#define AT_OFF   0
#define VEC_BASE (128*LDT)
#define VEC(i)   (VEC_BASE + (i)*128)
// 0 vz, 1 vaz, 2 vw0, 3 vt0, 4 vu1, 5 vwc, 6 vt2, 7 vvv, 8 vuw, 9 vdl, 10 vg1, 11 vg2
#define SC_OFF   (VEC_BASE + 12*128)
// scal: [0]=sig [1]=d2 [2]=s_uwg2 [3]=s_vg1 [4]=s_uwg1 [5] spare
//       [6..13]=epilogue wave sums [22]=GJ pivot
#define SMEM_FLOATS (SC_OFF + 24)
#define SMEM_BYTES  (SMEM_FLOATS * 4)        // 73,824 B

// ---------------------------------------------------------------------------
// Thread mapping (512 threads): w = t>>6 (8 waves), l = t&63
//   r  = 64*(w&1) + l      (row owned, 0..127)
//   q  = w>>1  (0..3), cb = 32*q  (column chunk)
// A, U, Ginv rows live in REGISTERS (32 floats each = 96 state regs). LDS
// holds A^T (for the two transpose matvecs) + step vectors. Matvec partials
// combine via LDS atomicAdd (consecutive lanes -> consecutive addresses,
// conflict-free; round 4 measured SQ_LDS_BANK_CONFLICT = 0).
//
// REGISTER CONTRACT (the round-1..4 killer): the backend defaults to a
// 2-blocks/CU register budget and SPILLS state (r1:(256,2)->128, r2:(512,4)->64,
// r3:(512,-)->128, r4:(1024,-)->64 VGPRs; 1.2-12.9 GB scratch HBM traffic).
// amdgpu_waves_per_eu(2,2) pins exactly 2 waves/EU = one 8-wave block/CU
// -> 256-VGPR budget, ~140 needed -> zero spill.
// ---------------------------------------------------------------------------

#define KATTR __attribute__((amdgpu_flat_work_group_size(512, 512), amdgpu_waves_per_eu(2, 2)))

// In-place Gauss-Jordan inverse of (A A^T + SIG2*I), 512 threads.
// Caller staged A row-major into T=[128][LDT] and synced. Destroys T;
// leaves Ginv in T (row-major). Internal map: rg = t>>2, cq = t&3, ccb = 32*cq.
__device__ __forceinline__ void ginv_inplace(float* sm, const int t) {
    float* T   = sm + AT_OFF;
    float* piv = sm + SC_OFF + 22;
    const int rg = t >> 2, cq = t & 3, ccb = cq << 5;
    float Gacc[32];
    #pragma unroll
    for (int j = 0; j < 32; ++j) Gacc[j] = 0.f;
    #pragma unroll 1
    for (int cc = 0; cc < 32; ++cc) {
        const float4 ar = *(const float4*)&T[rg*LDT + 4*cc];
        #pragma unroll
        for (int j = 0; j < 32; ++j) {
            const float4 br = *(const float4*)&T[(ccb + j)*LDT + 4*cc];
            Gacc[j] += ar.x*br.x + ar.y*br.y + ar.z*br.z + ar.w*br.w;
        }
    }
    #pragma unroll
    for (int j = 0; j < 32; ++j)
        if (ccb + j == rg) Gacc[j] += SIG2;
    __syncthreads();
    #pragma unroll
    for (int j4 = 0; j4 < 8; ++j4) {
        float4 v; v.x = Gacc[4*j4]; v.y = Gacc[4*j4+1]; v.z = Gacc[4*j4+2]; v.w = Gacc[4*j4+3];
        *(float4*)&T[rg*LDT + ccb + 4*j4] = v;
    }
    #pragma unroll 1
    for (int k = 0; k < 128; ++k) {
        const int kq = k >> 5;
        __syncthreads();
        if (rg == k && cq == kq) piv[0] = 1.0f / T[k*LDT + k];
        __syncthreads();
        if (rg == k) {
            const float pinv = piv[0];
            #pragma unroll
            for (int j4 = 0; j4 < 8; ++j4) {
                float4 g = *(float4*)&T[k*LDT + ccb + 4*j4];
                g.x *= pinv; g.y *= pinv; g.z *= pinv; g.w *= pinv;
                *(float4*)&T[k*LDT + ccb + 4*j4] = g;
            }
            if (cq == kq) T[k*LDT + k] = pinv;   // identity-column trick
        }
        __syncthreads();
        const float f = (rg == k) ? 0.f : T[rg*LDT + k];
        __syncthreads();
        if (rg != k) {
            #pragma unroll
            for (int j4 = 0; j4 < 8; ++j4) {
                float4 own = *(float4*)&T[rg*LDT + ccb + 4*j4];
                const float4 pv = *(const float4*)&T[k*LDT + ccb + 4*j4];
                own.x -= f*pv.x; own.y -= f*pv.y; own.z -= f*pv.z; own.w -= f*pv.w;
                *(float4*)&T[rg*LDT + ccb + 4*j4] = own;
            }
            if (cq == kq) T[rg*LDT + k] -= f;    // blind gave f - f*pinv; want -f*pinv
        }
    }
    __syncthreads();
}

__global__ KATTR void gpm_setup(const float* __restrict__ mean0,
                                float* __restrict__ ginv0) {
    extern __shared__ float sm[];
    float* T = sm + AT_OFF;
    const int t = threadIdx.x;
    const int rg = t >> 2, cq = t & 3, ccb = cq << 5;
    const float* src = mean0 + rg*CC + ccb;
    #pragma unroll
    for (int j4 = 0; j4 < 8; ++j4)
        *(float4*)&T[rg*LDT + ccb + 4*j4] = *(const float4*)&src[4*j4];
    __syncthreads();
    ginv_inplace(sm, t);
    #pragma unroll
    for (int j4 = 0; j4 < 8; ++j4)
        *(float4*)&ginv0[rg*CC + ccb + 4*j4] = *(const float4*)&T[rg*LDT + ccb + 4*j4];
}

// 3-level shuffle (8-lane groups) then 1-in-8 lanes atomic into a scalar slot
#define SC_ADD(slot, val) { float v_ = (val);                                 \
    v_ += __shfl_xor(v_, 1, 64); v_ += __shfl_xor(v_, 2, 64);                 \
    v_ += __shfl_xor(v_, 4, 64);                                              \
    if ((l & 7) == 0) atomicAdd(&scal[slot], v_); }

__global__ KATTR void gpm_main(
        const float* __restrict__ zin, const float* __restrict__ mean0,
        const float* __restrict__ lvar, float* __restrict__ out,
        const float* __restrict__ ginv0, const int use_ws) {
    extern __shared__ float sm[];
    float* At  = sm + AT_OFF;
    float* vz  = sm + VEC(0);
    float* vaz = sm + VEC(1);
    float* vw0 = sm + VEC(2);
    float* vt0 = sm + VEC(3);
    float* vu1 = sm + VEC(4);
    float* vwc = sm + VEC(5);
    float* vt2 = sm + VEC(6);
    float* vvv = sm + VEC(7);
    float* vuw = sm + VEC(8);
    float* vdl = sm + VEC(9);
    float* vg1 = sm + VEC(10);
    float* vg2 = sm + VEC(11);
    float* scal = sm + SC_OFF;

    const int t = threadIdx.x, b = blockIdx.x;
    const int w = t >> 6, l = t & 63;
    const int r  = ((w & 1) << 6) | l;
    const int q  = w >> 1;
    const int cb = q << 5;

    // zero all atomic-target vectors (12*128 = 1536) + scalar slots
    sm[VEC_BASE + t] = 0.f;
    sm[VEC_BASE + 512 + t] = 0.f;
    sm[VEC_BASE + 1024 + t] = 0.f;
    if (t < 24) scal[t] = 0.f;

    const float pvar = expf(lvar[0]) + EPSV;

    float Areg[32], Ureg[32], Greg[32];
    {
        const float* src = mean0 + r*CC + cb;
        #pragma unroll
        for (int j4 = 0; j4 < 8; ++j4) {
            const float4 v = *(const float4*)&src[4*j4];
            Areg[4*j4] = v.x; Areg[4*j4+1] = v.y; Areg[4*j4+2] = v.z; Areg[4*j4+3] = v.w;
        }
    }
    #pragma unroll
    for (int j = 0; j < 32; ++j) Ureg[j] = (cb + j == r) ? pvar : 0.f;

    if (use_ws) {
        const float* src = ginv0 + r*CC + cb;
        #pragma unroll
        for (int j4 = 0; j4 < 8; ++j4) {
            const float4 v = *(const float4*)&src[4*j4];
            Greg[4*j4] = v.x; Greg[4*j4+1] = v.y; Greg[4*j4+2] = v.z; Greg[4*j4+3] = v.w;
        }
    } else {
        // per-block fallback: stage A rows into At buffer, invert in place
        #pragma unroll
        for (int j4 = 0; j4 < 8; ++j4) {
            float4 v; v.x = Areg[4*j4]; v.y = Areg[4*j4+1]; v.z = Areg[4*j4+2]; v.w = Areg[4*j4+3];
            *(float4*)&At[r*LDT + cb + 4*j4] = v;
        }
        __syncthreads();
        ginv_inplace(sm, t);
        #pragma unroll
        for (int j4 = 0; j4 < 8; ++j4) {
            const float4 v = *(const float4*)&At[r*LDT + cb + 4*j4];
            Greg[4*j4] = v.x; Greg[4*j4+1] = v.y; Greg[4*j4+2] = v.z; Greg[4*j4+3] = v.w;
        }
        __syncthreads();       // done reading Ginv before At is overwritten
    }
    // At = A^T (column writes: consecutive lanes -> consecutive banks)
    #pragma unroll
    for (int j = 0; j < 32; ++j) At[(cb + j)*LDT + r] = Areg[j];
    if (t < 32)
        *(float4*)&vz[4*t] = *(const float4*)&zin[(size_t)b*CC + 4*t];
    __syncthreads();

    #pragma unroll 1
    for (int e = 0; e < EE; ++e) {
        // ---- L1: az = A z ; re-init this step's late accumulators ----
        {
            float s = 0.f;
            #pragma unroll
            for (int j4 = 0; j4 < 8; ++j4) {
                const float4 x = *(const float4*)&vz[cb + 4*j4];
                s += Areg[4*j4]*x.x + Areg[4*j4+1]*x.y + Areg[4*j4+2]*x.z + Areg[4*j4+3]*x.w;
            }
            atomicAdd(&vaz[r], s);
            if (t < 128) { vuw[t] = 0.f; vg1[t] = 0.f; vg2[t] = 0.f; }
            if (t == 256) { scal[0] = SIG2; scal[1] = 0.f; scal[2] = 0.f; scal[3] = 0.f; scal[4] = 0.f; }
        }
        __syncthreads();
        // ---- L2: w0 = Ginv az ----
        {
            float s = 0.f;
            #pragma unroll
            for (int j4 = 0; j4 < 8; ++j4) {
                const float4 x = *(const float4*)&vaz[cb + 4*j4];
                s += Greg[4*j4]*x.x + Greg[4*j4+1]*x.y + Greg[4*j4+2]*x.z + Greg[4*j4+3]*x.w;
            }
            atomicAdd(&vw0[r], s);
        }
        __syncthreads();
        // ---- L3: t0 = A^T w0 (rows of At) ----
        {
            float s = 0.f;
            #pragma unroll
            for (int j4 = 0; j4 < 8; ++j4) {
                const float4 a = *(const float4*)&At[r*LDT + cb + 4*j4];
                const float4 x = *(const float4*)&vw0[cb + 4*j4];
                s += a.x*x.x + a.y*x.y + a.z*x.z + a.w*x.w;
            }
            atomicAdd(&vt0[r], s);
        }
        __syncthreads();
        // ---- L4: u1 = A t0 ----
        {
            float s = 0.f;
            #pragma unroll
            for (int j4 = 0; j4 < 8; ++j4) {
                const float4 x = *(const float4*)&vt0[cb + 4*j4];
                s += Areg[4*j4]*x.x + Areg[4*j4+1]*x.y + Areg[4*j4+2]*x.z + Areg[4*j4+3]*x.w;
            }
            atomicAdd(&vu1[r], s);
        }
        __syncthreads();
        // ---- L5: wc = Ginv rr, rr = az - u1 - SIG2*w0 (fused reads) ----
        {
            float s = 0.f;
            #pragma unroll
            for (int j4 = 0; j4 < 8; ++j4) {
                const float4 az4 = *(const float4*)&vaz[cb + 4*j4];
                const float4 u14 = *(const float4*)&vu1[cb + 4*j4];
                const float4 w04 = *(const float4*)&vw0[cb + 4*j4];
                s += Greg[4*j4]  *(az4.x - u14.x - SIG2*w04.x)
                   + Greg[4*j4+1]*(az4.y - u14.y - SIG2*w04.y)
                   + Greg[4*j4+2]*(az4.z - u14.z - SIG2*w04.z)
                   + Greg[4*j4+3]*(az4.w - u14.w - SIG2*w04.w);
            }
            atomicAdd(&vwc[r], s);
        }
        __syncthreads();
        // ---- L6: t2 = A^T w ; uw = U w ; sig   (w = w0 + wc) ----
        {
            float s1 = 0.f, s2 = 0.f;
            #pragma unroll
            for (int j4 = 0; j4 < 8; ++j4) {
                const float4 a   = *(const float4*)&At[r*LDT + cb + 4*j4];
                const float4 w04 = *(const float4*)&vw0[cb + 4*j4];
                const float4 wc4 = *(const float4*)&vwc[cb + 4*j4];
                const float wx = w04.x + wc4.x, wy = w04.y + wc4.y;
                const float wz = w04.z + wc4.z, ww = w04.w + wc4.w;
                s1 += a.x*wx + a.y*wy + a.z*wz + a.w*ww;
                s2 += Ureg[4*j4]*wx + Ureg[4*j4+1]*wy + Ureg[4*j4+2]*wz + Ureg[4*j4+3]*ww;
            }
            atomicAdd(&vt2[r], s1);
            atomicAdd(&vuw[r], s2);
            const float w_r = vw0[r] + vwc[r];
            SC_ADD(0, s2 * w_r);                       // sig partial
        }
        __syncthreads();
        // ---- L7: vv = A dl (dl = z - t2) ; g2 = Ginv uw ; s_uwg2 ; d2 ; vdl ----
        {
            float s1 = 0.f, s2 = 0.f;
            #pragma unroll
            for (int j4 = 0; j4 < 8; ++j4) {
                const float4 z4  = *(const float4*)&vz[cb + 4*j4];
                const float4 t24 = *(const float4*)&vt2[cb + 4*j4];
                s1 += Areg[4*j4]  *(z4.x - t24.x) + Areg[4*j4+1]*(z4.y - t24.y)
                    + Areg[4*j4+2]*(z4.z - t24.z) + Areg[4*j4+3]*(z4.w - t24.w);
                const float4 u4  = *(const float4*)&vuw[cb + 4*j4];
                s2 += Greg[4*j4]*u4.x + Greg[4*j4+1]*u4.y + Greg[4*j4+2]*u4.z + Greg[4*j4+3]*u4.w;
            }
            atomicAdd(&vvv[r], s1);
            atomicAdd(&vg2[r], s2);
            SC_ADD(2, s2 * vuw[r]);                    // s_uwg2 partial
            if (t < 128) {
                const float dlv = vz[t] - vt2[t];
                vdl[t] = dlv;
                float d_ = dlv * dlv;
                d_ += __shfl_xor(d_, 1, 64); d_ += __shfl_xor(d_, 2, 64); d_ += __shfl_xor(d_, 4, 64);
                if ((l & 7) == 0) atomicAdd(&scal[1], d_);   // d2 partial
            }
        }
        __syncthreads();
        // ---- L8: g1 = Ginv vv ; s_vg1 ; s_uwg1 ----
        {
            float s = 0.f;
            #pragma unroll
            for (int j4 = 0; j4 < 8; ++j4) {
                const float4 x = *(const float4*)&vvv[cb + 4*j4];
                s += Greg[4*j4]*x.x + Greg[4*j4+1]*x.y + Greg[4*j4+2]*x.z + Greg[4*j4+3]*x.w;
            }
            atomicAdd(&vg1[r], s);
            SC_ADD(3, s * vvv[r]);                     // s_vg1 partial
            SC_ADD(4, s * vuw[r]);                     // s_uwg1 partial
        }
        __syncthreads();
        // ---- L9: rank updates of A,U,Ginv ; zero next accumulators ; next z ----
        {
            const float sig = scal[0];
            const float inv_sig = 1.0f / sig;
            const float d2v = scal[1];
            const float s_uwg2 = scal[2], s_vg1 = scal[3], s_uwg1 = scal[4];
            // 2x2 Woodbury capacitance: G_new = G + v c^T + c v^T + d2 c c^T
            const float b11 = s_vg1 - d2v;
            const float b12 = 1.0f + s_uwg1*inv_sig;
            const float b22 = s_uwg2*inv_sig*inv_sig;
            const float idet = 1.0f / (b11*b22 - b12*b12);
            const float K11 = b22*idet, K12v = -b12*idet, K22 = b11*idet;
            const float k12s = K12v*inv_sig, k22s = K22*inv_sig*inv_sig;
            const float cr  = vuw[r]*inv_sig;
            const float g1r = vg1[r], g2r = vg2[r];
            const float ar_ = K11*g1r + k12s*g2r;
            const float br_ = k12s*g1r + k22s*g2r;
            #pragma unroll
            for (int j4 = 0; j4 < 8; ++j4) {
                const float4 dd = *(const float4*)&vdl[cb + 4*j4];
                Areg[4*j4]   += cr*dd.x; Areg[4*j4+1] += cr*dd.y;
                Areg[4*j4+2] += cr*dd.z; Areg[4*j4+3] += cr*dd.w;
                const float4 uu = *(const float4*)&vuw[cb + 4*j4];
                Ureg[4*j4]   -= cr*uu.x; Ureg[4*j4+1] -= cr*uu.y;
                Ureg[4*j4+2] -= cr*uu.z; Ureg[4*j4+3] -= cr*uu.w;
                const float4 q1 = *(const float4*)&vg1[cb + 4*j4];
                const float4 q2 = *(const float4*)&vg2[cb + 4*j4];
                Greg[4*j4]   -= ar_*q1.x + br_*q2.x;
                Greg[4*j4+1] -= ar_*q1.y + br_*q2.y;
                Greg[4*j4+2] -= ar_*q1.z + br_*q2.z;
                Greg[4*j4+3] -= ar_*q1.w + br_*q2.w;
            }
            // write-through A^T
            #pragma unroll
            for (int j = 0; j < 32; ++j) At[(cb + j)*LDT + r] = Areg[j];
            // zero vaz,vw0,vt0,vu1,vwc,vt2,vvv (slots 1..7 = 896 floats)
            (sm + VEC(1))[t] = 0.f;
            if (t < 384) (sm + VEC(1))[512 + t] = 0.f;
            if (t < 32 && e + 1 < EE)
                *(float4*)&vz[4*t] = *(const float4*)&zin[((size_t)(e+1)*BB + b)*CC + 4*t];
        }
        __syncthreads();
    }

    // epilogue: post_mean from Areg
    {
        float* dst = out + (size_t)b*(MM*CC) + r*CC + cb;
        #pragma unroll
        for (int j4 = 0; j4 < 8; ++j4) {
            float4 v; v.x = Areg[4*j4]; v.y = Areg[4*j4+1]; v.z = Areg[4*j4+2]; v.w = Areg[4*j4+3];
            *(float4*)&dst[4*j4] = v;
        }
    }
    // post_cov from Ureg + diag extraction (static indexing)
    float qd = 1.f;
    {
        float* dst = out + (size_t)BB*(MM*CC) + (size_t)b*(MM*MM) + r*MM + cb;
        #pragma unroll
        for (int j4 = 0; j4 < 8; ++j4) {
            float4 v; v.x = Ureg[4*j4]; v.y = Ureg[4*j4+1]; v.z = Ureg[4*j4+2]; v.w = Ureg[4*j4+3];
            *(float4*)&dst[4*j4] = v;
            if (cb + 4*j4     == r) qd = v.x;
            if (cb + 4*j4 + 1 == r) qd = v.y;
            if (cb + 4*j4 + 2 == r) qd = v.z;
            if (cb + 4*j4 + 3 == r) qd = v.w;
        }
    }
    // dkl = mean_b[ C*sum(q/p) + sum((A-A0)^2)/p - C*M + C*sum(log p - log q) ]
    {
        const float inv_p = 1.0f / pvar;
        float acc = 0.f;
        const float* src = mean0 + r*CC + cb;
        #pragma unroll
        for (int j4 = 0; j4 < 8; ++j4) {
            const float4 a0 = *(const float4*)&src[4*j4];
            const float dx = Areg[4*j4]   - a0.x, dy = Areg[4*j4+1] - a0.y;
            const float dz = Areg[4*j4+2] - a0.z, dw = Areg[4*j4+3] - a0.w;
            acc += dx*dx + dy*dy + dz*dz + dw*dw;
        }
        float local = acc * inv_p;
        if (q == (r >> 5))   // owner of diagonal element of row r
            local += (float)CC * (qd*inv_p + logf(pvar) - logf(qd));
        #pragma unroll
        for (int m2 = 1; m2 < 64; m2 <<= 1) local += __shfl_xor(local, m2, 64);
        if (l == 0) scal[6 + w] = local;
        __syncthreads();
        if (t == 0) {
            float tot = 0.f;
            #pragma unroll
            for (int i = 0; i < 8; ++i) tot += scal[6 + i];
            tot -= (float)(CC*MM);
            atomicAdd(out + (size_t)2*BB*MM*CC, tot * (1.0f/(float)BB));
        }
    }
}

extern "C" void kernel_launch(void* const* d_in, const int* in_sizes, int n_in,
                              void* d_out, int out_size, void* d_ws, size_t ws_size,
                              hipStream_t stream) {
    (void)in_sizes; (void)n_in; (void)out_size;
    const float* zin   = (const float*)d_in[0];
    const float* mean0 = (const float*)d_in[1];
    const float* lvar  = (const float*)d_in[2];
    float* out = (float*)d_out;
    float* dkl = out + (size_t)2*BB*MM*CC;
    const int use_ws = (d_ws != nullptr && ws_size >= (size_t)MM*MM*4) ? 1 : 0;
    float* ginv0 = (float*)d_ws;

    hipFuncSetAttribute((const void*)gpm_setup, hipFuncAttributeMaxDynamicSharedMemorySize, SMEM_BYTES);
    hipFuncSetAttribute((const void*)gpm_main,  hipFuncAttributeMaxDynamicSharedMemorySize, SMEM_BYTES);

    hipMemsetAsync(dkl, 0, sizeof(float), stream);
    if (use_ws)
        gpm_setup<<<1, 512, SMEM_BYTES, stream>>>(mean0, ginv0);
    gpm_main<<<BB, 512, SMEM_BYTES, stream>>>(zin, mean0, lvar, out, ginv0, use_ws);
}

// Round 6
// 2047.276 us; speedup vs baseline: 2.0655x; 2.0188x over previous
//
#include <hip/hip_runtime.h>
#include <math.h>

// Problem constants (E,B,M,C) = (64, 512, 128, 128), sigma=0.5, eps=1e-6
#define MM   128
#define CC   128
#define EE   64
#define BB   512
#define LDT  132          // padded row stride for At/U in LDS (b128 row reads measured conflict-free)
#define SIG2 0.25f
#define EPSV 1e-6f

// LDS layout (floats): At[128][132] + U[128][132] + 10 vectors of 128 + 24 scalars
#define AT_OFF   0
#define U_OFF    (128*LDT)
#define VEC_BASE (2*128*LDT)
#define VEC(i)   (VEC_BASE + (i)*128)
// vec order: 0 vz, 1 vaz, 2 vw0, 3 vt0, 4 vvv, 5 vu1(rr), 6 vt2(dl), 7 vuw, 8 vg1, 9 vg2
#define SC_OFF   (VEC_BASE + 10*128)
// scal: [0]=sig [1]=d2 [2]=s_uwg2 [3]=s_vg1 [4]=s_uwg1  [6..13]=epilogue wave sums [22]=GJ pivot
#define SMEM_FLOATS (SC_OFF + 24)
#define SMEM_BYTES  (SMEM_FLOATS * 4)    // 140,384 B -> 1 block/CU (160 KB LDS)

// ---------------------------------------------------------------------------
// 512 threads: w = t>>6 (8 waves), l = t&63
//   r = 64*(w&1)+l (row owned), q = w>>1 (0..3), cb = 32*q (column chunk)
// REGISTERS: Areg[32] (mean row chunk), Greg[32] (Ginv row chunk)  = 64 state.
// LDS: At (transpose matvecs), U (cov; 2 touches/step), step vectors.
// REGISTER CONTRACT (r1-r5 lesson): allocator budget lands at 2x min
// waves/EU (feasibility floor 2 for 8-wave blocks) = 128 VGPRs. This kernel
// is DESIGNED to live in <=128: 64 state + ~30 temps. U in LDS is what buys
// the headroom (r5 kept it in regs: 96 state -> ~10-reg spill -> 3.4 GB rmw).
// ---------------------------------------------------------------------------
#define KATTR __attribute__((amdgpu_flat_work_group_size(512, 512), amdgpu_waves_per_eu(1, 2)))

// In-place Gauss-Jordan inverse of (A A^T + SIG2*I), 512 threads.
// A staged row-major in T=[128][LDT]; destroys T; leaves Ginv in T.
// Map: rg = t>>2, cq = t&3, ccb = 32*cq.
__device__ __forceinline__ void ginv_inplace(float* sm, const int t) {
    float* T   = sm + AT_OFF;
    float* piv = sm + SC_OFF + 22;
    const int rg = t >> 2, cq = t & 3, ccb = cq << 5;
    float Gacc[32];
    #pragma unroll
    for (int j = 0; j < 32; ++j) Gacc[j] = 0.f;
    #pragma unroll 1
    for (int cc = 0; cc < 32; ++cc) {
        const float4 ar = *(const float4*)&T[rg*LDT + 4*cc];
        #pragma unroll
        for (int j = 0; j < 32; ++j) {
            const float4 br = *(const float4*)&T[(ccb + j)*LDT + 4*cc];
            Gacc[j] += ar.x*br.x + ar.y*br.y + ar.z*br.z + ar.w*br.w;
        }
    }
    #pragma unroll
    for (int j = 0; j < 32; ++j)
        if (ccb + j == rg) Gacc[j] += SIG2;
    __syncthreads();
    #pragma unroll
    for (int j4 = 0; j4 < 8; ++j4) {
        float4 v; v.x = Gacc[4*j4]; v.y = Gacc[4*j4+1]; v.z = Gacc[4*j4+2]; v.w = Gacc[4*j4+3];
        *(float4*)&T[rg*LDT + ccb + 4*j4] = v;
    }
    #pragma unroll 1
    for (int k = 0; k < 128; ++k) {
        const int kq = k >> 5;
        __syncthreads();
        if (rg == k && cq == kq) piv[0] = 1.0f / T[k*LDT + k];
        __syncthreads();
        if (rg == k) {
            const float pinv = piv[0];
            #pragma unroll
            for (int j4 = 0; j4 < 8; ++j4) {
                float4 g = *(float4*)&T[k*LDT + ccb + 4*j4];
                g.x *= pinv; g.y *= pinv; g.z *= pinv; g.w *= pinv;
                *(float4*)&T[k*LDT + ccb + 4*j4] = g;
            }
            if (cq == kq) T[k*LDT + k] = pinv;   // identity-column trick
        }
        __syncthreads();
        const float f = (rg == k) ? 0.f : T[rg*LDT + k];
        __syncthreads();
        if (rg != k) {
            #pragma unroll
            for (int j4 = 0; j4 < 8; ++j4) {
                float4 own = *(float4*)&T[rg*LDT + ccb + 4*j4];
                const float4 pv = *(const float4*)&T[k*LDT + ccb + 4*j4];
                own.x -= f*pv.x; own.y -= f*pv.y; own.z -= f*pv.z; own.w -= f*pv.w;
                *(float4*)&T[rg*LDT + ccb + 4*j4] = own;
            }
            if (cq == kq) T[rg*LDT + k] -= f;    // blind gave f - f*pinv; want -f*pinv
        }
    }
    __syncthreads();
}

__global__ KATTR void gpm_setup(const float* __restrict__ mean0,
                                float* __restrict__ ginv0) {
    extern __shared__ float sm[];
    float* T = sm + AT_OFF;
    const int t = threadIdx.x;
    const int rg = t >> 2, cq = t & 3, ccb = cq << 5;
    const float* src = mean0 + rg*CC + ccb;
    #pragma unroll
    for (int j4 = 0; j4 < 8; ++j4)
        *(float4*)&T[rg*LDT + ccb + 4*j4] = *(const float4*)&src[4*j4];
    __syncthreads();
    ginv_inplace(sm, t);
    #pragma unroll
    for (int j4 = 0; j4 < 8; ++j4)
        *(float4*)&ginv0[rg*CC + ccb + 4*j4] = *(const float4*)&T[rg*LDT + ccb + 4*j4];
}

// 3-level shuffle (8-lane groups) then 1-in-8 lanes atomic into a scalar slot
#define SC_ADD(slot, val) { float v_ = (val);                                 \
    v_ += __shfl_xor(v_, 1, 64); v_ += __shfl_xor(v_, 2, 64);                 \
    v_ += __shfl_xor(v_, 4, 64);                                              \
    if ((l & 7) == 0) atomicAdd(&scal[slot], v_); }

__global__ KATTR void gpm_main(
        const float* __restrict__ zin, const float* __restrict__ mean0,
        const float* __restrict__ lvar, float* __restrict__ out,
        const float* __restrict__ ginv0, const int use_ws) {
    extern __shared__ float sm[];
    float* At  = sm + AT_OFF;
    float* U   = sm + U_OFF;
    float* vz  = sm + VEC(0);
    float* vaz = sm + VEC(1);
    float* vw0 = sm + VEC(2);   // becomes w after L5
    float* vt0 = sm + VEC(3);
    float* vvv = sm + VEC(4);
    float* vu1 = sm + VEC(5);   // pre-init az - SIG2*w0; becomes rr after L4
    float* vt2 = sm + VEC(6);   // pre-init z;            becomes dl after L6
    float* vuw = sm + VEC(7);
    float* vg1 = sm + VEC(8);
    float* vg2 = sm + VEC(9);
    float* scal = sm + SC_OFF;

    const int t = threadIdx.x, b = blockIdx.x;
    const int w = t >> 6, l = t & 63;
    const int r  = ((w & 1) << 6) | l;
    const int q  = w >> 1;
    const int cb = q << 5;

    // zero accumulator vectors VEC(1)..VEC(9) (1152 floats) + scalar slots
    sm[VEC(1) + t] = 0.f;
    sm[VEC(1) + 512 + t] = 0.f;
    if (t < 128) sm[VEC(1) + 1024 + t] = 0.f;
    if (t < 24)  scal[t] = 0.f;

    const float pvar = expf(lvar[0]) + EPSV;

    float Areg[32], Greg[32];
    {
        const float* src = mean0 + r*CC + cb;
        #pragma unroll
        for (int j4 = 0; j4 < 8; ++j4) {
            const float4 v = *(const float4*)&src[4*j4];
            Areg[4*j4] = v.x; Areg[4*j4+1] = v.y; Areg[4*j4+2] = v.z; Areg[4*j4+3] = v.w;
        }
    }
    // U = pvar * I  (row r, cols [cb,cb+32))
    {
        const float4 z4 = {0.f, 0.f, 0.f, 0.f};
        #pragma unroll
        for (int j4 = 0; j4 < 8; ++j4)
            *(float4*)&U[r*LDT + cb + 4*j4] = z4;
        if (r >= cb && r < cb + 32) U[r*LDT + r] = pvar;
    }

    if (use_ws) {
        const float* src = ginv0 + r*CC + cb;
        #pragma unroll
        for (int j4 = 0; j4 < 8; ++j4) {
            const float4 v = *(const float4*)&src[4*j4];
            Greg[4*j4] = v.x; Greg[4*j4+1] = v.y; Greg[4*j4+2] = v.z; Greg[4*j4+3] = v.w;
        }
    } else {
        // fallback: stage A into At buffer, invert in place, read back
        #pragma unroll
        for (int j4 = 0; j4 < 8; ++j4) {
            float4 v; v.x = Areg[4*j4]; v.y = Areg[4*j4+1]; v.z = Areg[4*j4+2]; v.w = Areg[4*j4+3];
            *(float4*)&At[r*LDT + cb + 4*j4] = v;
        }
        __syncthreads();
        ginv_inplace(sm, t);
        #pragma unroll
        for (int j4 = 0; j4 < 8; ++j4) {
            const float4 v = *(const float4*)&At[r*LDT + cb + 4*j4];
            Greg[4*j4] = v.x; Greg[4*j4+1] = v.y; Greg[4*j4+2] = v.z; Greg[4*j4+3] = v.w;
        }
        __syncthreads();       // done reading Ginv before At is overwritten
    }
    // At = A^T (consecutive lanes -> consecutive addresses)
    #pragma unroll
    for (int j = 0; j < 32; ++j) At[(cb + j)*LDT + r] = Areg[j];
    if (t < 32)
        *(float4*)&vz[4*t] = *(const float4*)&zin[(size_t)b*CC + 4*t];
    __syncthreads();

    #pragma unroll 1
    for (int e = 0; e < EE; ++e) {
        // ---- L1: az = A z ; zero late accumulators (vuw,vg1,vg2) ; reset scalars ----
        {
            float s = 0.f;
            #pragma unroll
            for (int j4 = 0; j4 < 8; ++j4) {
                const float4 x = *(const float4*)&vz[cb + 4*j4];
                s += Areg[4*j4]*x.x + Areg[4*j4+1]*x.y + Areg[4*j4+2]*x.z + Areg[4*j4+3]*x.w;
            }
            atomicAdd(&vaz[r], s);
            if (t < 384) (sm + VEC(7))[t] = 0.f;       // vuw, vg1, vg2
            if (t == 448) { scal[0] = SIG2; scal[1] = 0.f; scal[2] = 0.f; scal[3] = 0.f; scal[4] = 0.f; }
        }
        __syncthreads();
        // ---- L2: w0 = Ginv az ----
        {
            float s = 0.f;
            #pragma unroll
            for (int j4 = 0; j4 < 8; ++j4) {
                const float4 x = *(const float4*)&vaz[cb + 4*j4];
                s += Greg[4*j4]*x.x + Greg[4*j4+1]*x.y + Greg[4*j4+2]*x.z + Greg[4*j4+3]*x.w;
            }
            atomicAdd(&vw0[r], s);
        }
        __syncthreads();
        // ---- L3: t0 = A^T w0 ; pre-init vu1 = az - SIG2*w0 ----
        {
            float s = 0.f;
            #pragma unroll
            for (int j4 = 0; j4 < 8; ++j4) {
                const float4 a = *(const float4*)&At[r*LDT + cb + 4*j4];
                const float4 x = *(const float4*)&vw0[cb + 4*j4];
                s += a.x*x.x + a.y*x.y + a.z*x.z + a.w*x.w;
            }
            atomicAdd(&vt0[r], s);
            if (t < 128) vu1[t] = vaz[t] - SIG2*vw0[t];
        }
        __syncthreads();
        // ---- L4: vu1 -= A t0   (after barrier: vu1 = rr = az - A A^T w0 - SIG2 w0) ----
        {
            float s = 0.f;
            #pragma unroll
            for (int j4 = 0; j4 < 8; ++j4) {
                const float4 x = *(const float4*)&vt0[cb + 4*j4];
                s += Areg[4*j4]*x.x + Areg[4*j4+1]*x.y + Areg[4*j4+2]*x.z + Areg[4*j4+3]*x.w;
            }
            atomicAdd(&vu1[r], -s);
        }
        __syncthreads();
        // ---- L5: vw0 += Ginv rr  (after barrier: vw0 = w) ; pre-init vt2 = z ----
        {
            float s = 0.f;
            #pragma unroll
            for (int j4 = 0; j4 < 8; ++j4) {
                const float4 x = *(const float4*)&vu1[cb + 4*j4];
                s += Greg[4*j4]*x.x + Greg[4*j4+1]*x.y + Greg[4*j4+2]*x.z + Greg[4*j4+3]*x.w;
            }
            atomicAdd(&vw0[r], s);
            if (t < 128) vt2[t] = vz[t];
        }
        __syncthreads();
        // ---- L6: vt2 -= A^T w (-> dl) ; uw = U w ; sig partial ----
        {
            float s1 = 0.f, s2 = 0.f;
            #pragma unroll
            for (int j4 = 0; j4 < 8; ++j4) {
                const float4 a = *(const float4*)&At[r*LDT + cb + 4*j4];
                const float4 u = *(const float4*)&U[r*LDT + cb + 4*j4];
                const float4 x = *(const float4*)&vw0[cb + 4*j4];
                s1 += a.x*x.x + a.y*x.y + a.z*x.z + a.w*x.w;
                s2 += u.x*x.x + u.y*x.y + u.z*x.z + u.w*x.w;
            }
            atomicAdd(&vt2[r], -s1);
            atomicAdd(&vuw[r], s2);
            SC_ADD(0, s2 * vw0[r]);                    // sig partial
        }
        __syncthreads();
        // ---- L7: vv = A dl ; g2 = Ginv uw ; s_uwg2 ; d2 ----
        {
            float s1 = 0.f, s2 = 0.f;
            #pragma unroll
            for (int j4 = 0; j4 < 8; ++j4) {
                const float4 d4 = *(const float4*)&vt2[cb + 4*j4];
                const float4 u4 = *(const float4*)&vuw[cb + 4*j4];
                s1 += Areg[4*j4]*d4.x + Areg[4*j4+1]*d4.y + Areg[4*j4+2]*d4.z + Areg[4*j4+3]*d4.w;
                s2 += Greg[4*j4]*u4.x + Greg[4*j4+1]*u4.y + Greg[4*j4+2]*u4.z + Greg[4*j4+3]*u4.w;
            }
            atomicAdd(&vvv[r], s1);
            atomicAdd(&vg2[r], s2);
            SC_ADD(2, s2 * vuw[r]);                    // s_uwg2 partial
            if (t < 128) {
                float d_ = vt2[t]; d_ *= d_;
                d_ += __shfl_xor(d_, 1, 64); d_ += __shfl_xor(d_, 2, 64); d_ += __shfl_xor(d_, 4, 64);
                if ((l & 7) == 0) atomicAdd(&scal[1], d_);   // d2 partial
            }
        }
        __syncthreads();
        // ---- L8: g1 = Ginv vv ; s_vg1 ; s_uwg1 ----
        {
            float s = 0.f;
            #pragma unroll
            for (int j4 = 0; j4 < 8; ++j4) {
                const float4 x = *(const float4*)&vvv[cb + 4*j4];
                s += Greg[4*j4]*x.x + Greg[4*j4+1]*x.y + Greg[4*j4+2]*x.z + Greg[4*j4+3]*x.w;
            }
            atomicAdd(&vg1[r], s);
            SC_ADD(3, s * vvv[r]);                     // s_vg1 partial
            SC_ADD(4, s * vuw[r]);                     // s_uwg1 partial
        }
        __syncthreads();
        // ---- L9: rank updates of A (regs+At), U (LDS rmw), Ginv (regs) ----
        {
            const float sig = scal[0];
            const float inv_sig = 1.0f / sig;
            const float d2v = scal[1];
            const float s_uwg2 = scal[2], s_vg1 = scal[3], s_uwg1 = scal[4];
            // 2x2 Woodbury capacitance: G_new = G + v c^T + c v^T + d2 c c^T
            const float b11 = s_vg1 - d2v;
            const float b12 = 1.0f + s_uwg1*inv_sig;
            const float b22 = s_uwg2*inv_sig*inv_sig;
            const float idet = 1.0f / (b11*b22 - b12*b12);
            const float K11 = b22*idet, K12v = -b12*idet, K22 = b11*idet;
            const float k12s = K12v*inv_sig, k22s = K22*inv_sig*inv_sig;
            const float cr  = vuw[r]*inv_sig;
            const float g1r = vg1[r], g2r = vg2[r];
            const float ar_ = K11*g1r + k12s*g2r;
            const float br_ = k12s*g1r + k22s*g2r;
            // A += c dl^T (regs)
            #pragma unroll
            for (int j4 = 0; j4 < 8; ++j4) {
                const float4 dd = *(const float4*)&vt2[cb + 4*j4];
                Areg[4*j4]   += cr*dd.x; Areg[4*j4+1] += cr*dd.y;
                Areg[4*j4+2] += cr*dd.z; Areg[4*j4+3] += cr*dd.w;
            }
            // U -= c uw^T (LDS rmw)
            #pragma unroll
            for (int j4 = 0; j4 < 8; ++j4) {
                const float4 uu = *(const float4*)&vuw[cb + 4*j4];
                float4 u = *(float4*)&U[r*LDT + cb + 4*j4];
                u.x -= cr*uu.x; u.y -= cr*uu.y; u.z -= cr*uu.z; u.w -= cr*uu.w;
                *(float4*)&U[r*LDT + cb + 4*j4] = u;
            }
            // Ginv -= [g1 g2s] K [g1 g2s]^T (regs)
            #pragma unroll
            for (int j4 = 0; j4 < 8; ++j4) {
                const float4 q1 = *(const float4*)&vg1[cb + 4*j4];
                const float4 q2 = *(const float4*)&vg2[cb + 4*j4];
                Greg[4*j4]   -= ar_*q1.x + br_*q2.x;
                Greg[4*j4+1] -= ar_*q1.y + br_*q2.y;
                Greg[4*j4+2] -= ar_*q1.z + br_*q2.z;
                Greg[4*j4+3] -= ar_*q1.w + br_*q2.w;
            }
            // write-through A^T
            #pragma unroll
            for (int j = 0; j < 32; ++j) At[(cb + j)*LDT + r] = Areg[j];
            // zero next step's early accumulators: vaz,vw0,vt0,vvv (VEC(1)..VEC(4))
            (sm + VEC(1))[t] = 0.f;
            if (t < 32 && e + 1 < EE)
                *(float4*)&vz[4*t] = *(const float4*)&zin[((size_t)(e+1)*BB + b)*CC + 4*t];
        }
        __syncthreads();
    }

    // epilogue: post_mean from Areg
    {
        float* dst = out + (size_t)b*(MM*CC) + r*CC + cb;
        #pragma unroll
        for (int j4 = 0; j4 < 8; ++j4) {
            float4 v; v.x = Areg[4*j4]; v.y = Areg[4*j4+1]; v.z = Areg[4*j4+2]; v.w = Areg[4*j4+3];
            *(float4*)&dst[4*j4] = v;
        }
    }
    // post_cov from U (LDS)
    {
        float* dst = out + (size_t)BB*(MM*CC) + (size_t)b*(MM*MM) + r*MM + cb;
        #pragma unroll
        for (int j4 = 0; j4 < 8; ++j4)
            *(float4*)&dst[4*j4] = *(const float4*)&U[r*LDT + cb + 4*j4];
    }
    // dkl = mean_b[ C*sum(q/p) + sum((A-A0)^2)/p - C*M + C*sum(log p - log q) ]
    {
        const float inv_p = 1.0f / pvar;
        float acc = 0.f;
        const float* src = mean0 + r*CC + cb;
        #pragma unroll
        for (int j4 = 0; j4 < 8; ++j4) {
            const float4 a0 = *(const float4*)&src[4*j4];
            const float dx = Areg[4*j4]   - a0.x, dy = Areg[4*j4+1] - a0.y;
            const float dz = Areg[4*j4+2] - a0.z, dw = Areg[4*j4+3] - a0.w;
            acc += dx*dx + dy*dy + dz*dz + dw*dw;
        }
        float local = acc * inv_p;
        if (q == (r >> 5)) {   // owner of diagonal element of row r
            const float qd = U[r*LDT + r];
            local += (float)CC * (qd*inv_p + logf(pvar) - logf(qd));
        }
        #pragma unroll
        for (int m2 = 1; m2 < 64; m2 <<= 1) local += __shfl_xor(local, m2, 64);
        if (l == 0) scal[6 + w] = local;
        __syncthreads();
        if (t == 0) {
            float tot = 0.f;
            #pragma unroll
            for (int i = 0; i < 8; ++i) tot += scal[6 + i];
            tot -= (float)(CC*MM);
            atomicAdd(out + (size_t)2*BB*MM*CC, tot * (1.0f/(float)BB));
        }
    }
}

extern "C" void kernel_launch(void* const* d_in, const int* in_sizes, int n_in,
                              void* d_out, int out_size, void* d_ws, size_t ws_size,
                              hipStream_t stream) {
    (void)in_sizes; (void)n_in; (void)out_size;
    const float* zin   = (const float*)d_in[0];
    const float* mean0 = (const float*)d_in[1];
    const float* lvar  = (const float*)d_in[2];
    float* out = (float*)d_out;
    float* dkl = out + (size_t)2*BB*MM*CC;
    const int use_ws = (d_ws != nullptr && ws_size >= (size_t)MM*MM*4) ? 1 : 0;
    float* ginv0 = (float*)d_ws;

    hipFuncSetAttribute((const void*)gpm_setup, hipFuncAttributeMaxDynamicSharedMemorySize, SMEM_BYTES);
    hipFuncSetAttribute((const void*)gpm_main,  hipFuncAttributeMaxDynamicSharedMemorySize, SMEM_BYTES);

    hipMemsetAsync(dkl, 0, sizeof(float), stream);
    if (use_ws)
        gpm_setup<<<1, 512, SMEM_BYTES, stream>>>(mean0, ginv0);
    gpm_main<<<BB, 512, SMEM_BYTES, stream>>>(zin, mean0, lvar, out, ginv0, use_ws);
}